// Round 10
// baseline (119.485 us; speedup 1.0000x reference)
//
#include <hip/hip_runtime.h>

#define Bn 16
#define Ln 128
#define Hn 256
#define Dn 256

// Output layout (flat fp32 concat, reference return order)
#define OFF_MASK   0          // (B,L,L) 262144
#define OFF_SMP    262144     // (B,L,L) 262144
#define OFF_ENT    524288     // (B,L,L) 262144
#define OFF_GRAPH  786432     // (L,L)   16384
#define OFF_LSE    802816     // scalar
#define OFF_EREG   802817     // (B,)    16

static __device__ __forceinline__ unsigned rotl32(unsigned x, int r) {
  return (x << r) | (x >> (32 - r));
}

// Threefry-2x32, 20 rounds, key = (0,1)  [jax.random.key(1)], partitionable
// random-bits path: counter = (hi=0, lo=flat_index), output = y0 ^ y1.
static __device__ __forceinline__ unsigned threefry_bits(unsigned c_hi, unsigned c_lo) {
  const unsigned ks0 = 0u, ks1 = 1u;
  const unsigned ks2 = 0u ^ 1u ^ 0x1BD11BDAu;
  unsigned x0 = c_hi + ks0;
  unsigned x1 = c_lo + ks1;
  x0 += x1; x1 = rotl32(x1, 13); x1 ^= x0;
  x0 += x1; x1 = rotl32(x1, 15); x1 ^= x0;
  x0 += x1; x1 = rotl32(x1, 26); x1 ^= x0;
  x0 += x1; x1 = rotl32(x1, 6);  x1 ^= x0;
  x0 += ks1; x1 += ks2 + 1u;
  x0 += x1; x1 = rotl32(x1, 17); x1 ^= x0;
  x0 += x1; x1 = rotl32(x1, 29); x1 ^= x0;
  x0 += x1; x1 = rotl32(x1, 16); x1 ^= x0;
  x0 += x1; x1 = rotl32(x1, 24); x1 ^= x0;
  x0 += ks2; x1 += ks0 + 2u;
  x0 += x1; x1 = rotl32(x1, 13); x1 ^= x0;
  x0 += x1; x1 = rotl32(x1, 15); x1 ^= x0;
  x0 += x1; x1 = rotl32(x1, 26); x1 ^= x0;
  x0 += x1; x1 = rotl32(x1, 6);  x1 ^= x0;
  x0 += ks0; x1 += ks1 + 3u;
  x0 += x1; x1 = rotl32(x1, 17); x1 ^= x0;
  x0 += x1; x1 = rotl32(x1, 29); x1 ^= x0;
  x0 += x1; x1 = rotl32(x1, 16); x1 ^= x0;
  x0 += x1; x1 = rotl32(x1, 24); x1 ^= x0;
  x0 += ks1; x1 += ks2 + 4u;
  x0 += x1; x1 = rotl32(x1, 13); x1 ^= x0;
  x0 += x1; x1 = rotl32(x1, 15); x1 ^= x0;
  x0 += x1; x1 = rotl32(x1, 26); x1 ^= x0;
  x0 += x1; x1 = rotl32(x1, 6);  x1 ^= x0;
  x0 += ks2; x1 += ks0 + 5u;
  return x0 ^ x1;
}

static __device__ __forceinline__ float softplus_f(float x) {
  // max(x,0) + log1p(exp(-|x|)); exact at |x|=1e8 (exp(-1e8)=0)
  return fmaxf(x, 0.0f) + log1pf(__expf(-fabsf(x)));
}

static __device__ __forceinline__ float fast_tanh(float x) {
  // tanh(x) = 2/(1+e^{-2x}) - 1; saturates correctly for |x| large
  float e = __expf(-2.0f * x);
  float r = __builtin_amdgcn_rcpf(1.0f + e);
  return fmaf(2.0f, r, -1.0f);
}

// fp32 projections, 4 rows per block (512 blocks = 2/CU), LDS-staged enc,
// graph + scalar-output zeroing fused in (harness poisons d_out with 0xAA).
// EXACT R9 proj math; fma order (h ascending) -> dl/dr bit-identical.
__global__ void proj_kernel(const float* __restrict__ enc,
                            const float* __restrict__ Wl,
                            const float* __restrict__ Wr,
                            float* __restrict__ dl,
                            float* __restrict__ dr,
                            float* __restrict__ out) {
  int gid = blockIdx.x * blockDim.x + threadIdx.x;
  if (gid < Ln * Ln) out[OFF_GRAPH + gid] = 0.0f;
  if (gid < 17) out[OFF_LSE + gid] = 0.0f;   // LSE + 16 EREG scalars

  int r0 = blockIdx.x * 4;     // 512 blocks x 4 rows = 2048 rows
  int d = threadIdx.x;         // 0..255
  __shared__ float encS[4][Hn];
  ((float4*)encS)[d] = ((const float4*)(enc + (size_t)r0 * Hn))[d];
  __syncthreads();

  float al[4] = {0.f, 0.f, 0.f, 0.f};
  float ar[4] = {0.f, 0.f, 0.f, 0.f};
  for (int h4 = 0; h4 < Hn / 4; ++h4) {
    float4 e[4];
#pragma unroll
    for (int r = 0; r < 4; ++r) e[r] = ((const float4*)encS[r])[h4];
#pragma unroll
    for (int q = 0; q < 4; ++q) {
      int h = h4 * 4 + q;
      float wl = Wl[h * Dn + d];
      float wr = Wr[h * Dn + d];
#pragma unroll
      for (int r = 0; r < 4; ++r) {
        float ev = (q == 0) ? e[r].x : (q == 1) ? e[r].y : (q == 2) ? e[r].z : e[r].w;
        al[r] = fmaf(ev, wl, al[r]);
        ar[r] = fmaf(ev, wr, ar[r]);
      }
    }
  }
#pragma unroll
  for (int r = 0; r < 4; ++r) {
    dl[(size_t)(r0 + r) * Dn + d] = al[r];
    dr[(size_t)(r0 + r) * Dn + d] = ar[r];
  }
}

// Grid 1024 = (b:16, iq:32, jseg:2); block = 4 i-rows x 64 j x 256 d.
// EXACT R9 pair math (mask/samples/entropy/graph bit-identical). The
// block-leader accumulates the two scalar outputs via PRE-SCALED fp32
// atomics directly into out — no finalize kernel, no ticket, no ws_acc.
__global__ void pair_kernel(const float* __restrict__ dl,
                            const float* __restrict__ dr,
                            const float* __restrict__ U,
                            const float* __restrict__ bias,
                            float* __restrict__ out) {
  int blk = blockIdx.x;          // b*64 + iq*2 + jseg
  int b = blk >> 6;              // 0..15
  int i0 = ((blk >> 1) & 31) * 4;
  int j0 = (blk & 1) * 64;
  int t = threadIdx.x;
  int dp = t & 15;
  int jj = t >> 4;

  __shared__ float dlS[4][Dn];       // 4 KB, cooperative coalesced stage
  __shared__ float pS[4][4 * 256];   // [row][tl*256 + jj*16 + dp], 16 KB
  __shared__ float redS[8];

  // stage dl rows i0..i0+3 with one coalesced float4 load per thread
  ((float4*)dlS)[t] = ((const float4*)(dl + (size_t)(b * Ln + i0) * Dn))[t];

  float Ur[16];
  {
    const float4* U4 = (const float4*)(U + dp * 16);
#pragma unroll
    for (int q = 0; q < 4; ++q) {
      float4 u = U4[q];
      Ur[4*q+0] = u.x; Ur[4*q+1] = u.y; Ur[4*q+2] = u.z; Ur[4*q+3] = u.w;
    }
  }
  __syncthreads();

  float dlr[4][16];
#pragma unroll
  for (int r = 0; r < 4; ++r) {
#pragma unroll
    for (int q = 0; q < 4; ++q) {
      float4 a = *(const float4*)&dlS[r][dp * 16 + q * 4];
      dlr[r][4*q+0] = a.x; dlr[r][4*q+1] = a.y; dlr[r][4*q+2] = a.z; dlr[r][4*q+3] = a.w;
    }
  }

  const float* drt = dr + (size_t)b * Ln * Dn + (size_t)(j0 + jj) * Dn + dp * 16;
#pragma unroll
  for (int tl = 0; tl < 4; ++tl) {
    const float4* drp = (const float4*)(drt + (size_t)tl * 16 * Dn);
    float a0 = 0.f, a1 = 0.f, a2 = 0.f, a3 = 0.f;
#pragma unroll
    for (int q = 0; q < 4; ++q) {
      float4 v = drp[q];
#pragma unroll
      for (int c = 0; c < 4; ++c) {
        float dv = (c == 0) ? v.x : (c == 1) ? v.y : (c == 2) ? v.z : v.w;
        float uv = Ur[4*q+c];
        a0 = fmaf(fast_tanh(dlr[0][4*q+c] + dv), uv, a0);
        a1 = fmaf(fast_tanh(dlr[1][4*q+c] + dv), uv, a1);
        a2 = fmaf(fast_tanh(dlr[2][4*q+c] + dv), uv, a2);
        a3 = fmaf(fast_tanh(dlr[3][4*q+c] + dv), uv, a3);
      }
    }
    int sa = tl * 256 + jj * 16 + dp;    // == tl*256 + t : conflict-free
    pS[0][sa] = a0; pS[1][sa] = a1; pS[2][sa] = a2; pS[3][sa] = a3;
  }
  __syncthreads();

  // epilogue: 256 outputs (4 rows x 64 j); thread t -> row = t>>6, jl = t&63
  int row = t >> 6;
  int jl = t & 63;
  int j = j0 + jl;
  const float* ps = &pS[row][(jl >> 4) * 256 + (jl & 15) * 16];
  float tot = 0.0f;
#pragma unroll
  for (int k = 0; k < 16; ++k) tot += ps[k];   // dp-ascending, same as R9
  int i = i0 + row;
  float l = tot + bias[0] - ((j == i) ? 1.0e8f : 0.0f);
  float e = __expf(-l);                       // l=-1e8 -> inf
  float p = __builtin_amdgcn_rcpf(1.0f + e);  // -> 0 on diagonal
  unsigned n = ((unsigned)(b * Ln + i) << 7) | (unsigned)j;
  unsigned bits = threefry_bits(0u, n);
  float u = __uint_as_float((bits >> 9) | 0x3f800000u) - 1.0f;
  float smp = (u < p) ? 1.0f : 0.0f;
  float sp_pos = softplus_f(l);
  float sp_neg = softplus_f(-l);
  float ent = p * sp_neg + (1.0f - p) * sp_pos;
  size_t idx = (size_t)(b * Ln + i) * Ln + j;
  out[OFF_MASK + idx] = l;
  out[OFF_SMP + idx] = smp;
  out[OFF_ENT + idx] = ent;
  atomicAdd(&out[OFF_GRAPH + i * Ln + j], smp * 0.0625f);
  float ent_v = ent;
  float lse_v = sp_pos - l * smp;

  // reduce over the 4 waves (all lanes valid)
#pragma unroll
  for (int off = 32; off > 0; off >>= 1) {
    ent_v += __shfl_down(ent_v, off);
    lse_v += __shfl_down(lse_v, off);
  }
  if ((t & 63) == 0) {
    redS[(t >> 6) * 2 + 0] = ent_v;
    redS[(t >> 6) * 2 + 1] = lse_v;
  }
  __syncthreads();
  if (t == 0) {
    float es = redS[0] + redS[2] + redS[4] + redS[6];
    float ls = redS[1] + redS[3] + redS[5] + redS[7];
    // pre-scaled: accumulated value IS the mean (ent: /L^2, lse: /(B*L^2))
    atomicAdd(&out[OFF_EREG + b], es * (1.0f / (Ln * Ln)));
    atomicAdd(&out[OFF_LSE], ls * (1.0f / (Bn * Ln * Ln)));
  }
}

extern "C" void kernel_launch(void* const* d_in, const int* in_sizes, int n_in,
                              void* d_out, int out_size, void* d_ws, size_t ws_size,
                              hipStream_t stream) {
  const float* enc = (const float*)d_in[0];
  const float* Wl = (const float*)d_in[1];
  const float* Wr = (const float*)d_in[2];
  const float* U = (const float*)d_in[3];
  const float* bias = (const float*)d_in[4];
  float* out = (float*)d_out;

  // ws layout: dl (2048*256 f32), dr (2048*256 f32)
  float* dl = (float*)d_ws;
  float* dr = dl + (size_t)Bn * Ln * Dn;

  proj_kernel<<<Bn * Ln / 4, 256, 0, stream>>>(enc, Wl, Wr, dl, dr, out);
  pair_kernel<<<Bn * Ln / 2, 256, 0, stream>>>(dl, dr, U, bias, out);
}

// Round 11
// 110.990 us; speedup vs baseline: 1.0765x; 1.0765x over previous
//
#include <hip/hip_runtime.h>

#define Bn 16
#define Ln 128
#define Hn 256
#define Dn 256

// Output layout (flat fp32 concat, reference return order)
#define OFF_MASK   0          // (B,L,L) 262144
#define OFF_SMP    262144     // (B,L,L) 262144
#define OFF_ENT    524288     // (B,L,L) 262144
#define OFF_GRAPH  786432     // (L,L)   16384
#define OFF_LSE    802816     // scalar
#define OFF_EREG   802817     // (B,)    16

static __device__ __forceinline__ unsigned rotl32(unsigned x, int r) {
  return (x << r) | (x >> (32 - r));
}

// Threefry-2x32, 20 rounds, key = (0,1)  [jax.random.key(1)], partitionable
// random-bits path: counter = (hi=0, lo=flat_index), output = y0 ^ y1.
static __device__ __forceinline__ unsigned threefry_bits(unsigned c_hi, unsigned c_lo) {
  const unsigned ks0 = 0u, ks1 = 1u;
  const unsigned ks2 = 0u ^ 1u ^ 0x1BD11BDAu;
  unsigned x0 = c_hi + ks0;
  unsigned x1 = c_lo + ks1;
  x0 += x1; x1 = rotl32(x1, 13); x1 ^= x0;
  x0 += x1; x1 = rotl32(x1, 15); x1 ^= x0;
  x0 += x1; x1 = rotl32(x1, 26); x1 ^= x0;
  x0 += x1; x1 = rotl32(x1, 6);  x1 ^= x0;
  x0 += ks1; x1 += ks2 + 1u;
  x0 += x1; x1 = rotl32(x1, 17); x1 ^= x0;
  x0 += x1; x1 = rotl32(x1, 29); x1 ^= x0;
  x0 += x1; x1 = rotl32(x1, 16); x1 ^= x0;
  x0 += x1; x1 = rotl32(x1, 24); x1 ^= x0;
  x0 += ks2; x1 += ks0 + 2u;
  x0 += x1; x1 = rotl32(x1, 13); x1 ^= x0;
  x0 += x1; x1 = rotl32(x1, 15); x1 ^= x0;
  x0 += x1; x1 = rotl32(x1, 26); x1 ^= x0;
  x0 += x1; x1 = rotl32(x1, 6);  x1 ^= x0;
  x0 += ks0; x1 += ks1 + 3u;
  x0 += x1; x1 = rotl32(x1, 17); x1 ^= x0;
  x0 += x1; x1 = rotl32(x1, 29); x1 ^= x0;
  x0 += x1; x1 = rotl32(x1, 16); x1 ^= x0;
  x0 += x1; x1 = rotl32(x1, 24); x1 ^= x0;
  x0 += ks1; x1 += ks2 + 4u;
  x0 += x1; x1 = rotl32(x1, 13); x1 ^= x0;
  x0 += x1; x1 = rotl32(x1, 15); x1 ^= x0;
  x0 += x1; x1 = rotl32(x1, 26); x1 ^= x0;
  x0 += x1; x1 = rotl32(x1, 6);  x1 ^= x0;
  x0 += ks2; x1 += ks0 + 5u;
  return x0 ^ x1;
}

static __device__ __forceinline__ float softplus_f(float x) {
  // max(x,0) + log1p(exp(-|x|)); exact at |x|=1e8 (exp(-1e8)=0)
  return fmaxf(x, 0.0f) + log1pf(__expf(-fabsf(x)));
}

static __device__ __forceinline__ float fast_tanh(float x) {
  // tanh(x) = 2/(1+e^{-2x}) - 1; saturates correctly for |x| large
  float e = __expf(-2.0f * x);
  float r = __builtin_amdgcn_rcpf(1.0f + e);
  return fmaf(2.0f, r, -1.0f);
}

// fp32 projections, 4 rows per block (512 blocks = 2/CU), LDS-staged enc,
// graph/accumulator zeroing fused in. EXACT R9 form (best measured:
// 112.2 us total). fma order (h ascending) -> dl/dr bit-identical.
__global__ void proj_kernel(const float* __restrict__ enc,
                            const float* __restrict__ Wl,
                            const float* __restrict__ Wr,
                            float* __restrict__ dl,
                            float* __restrict__ dr,
                            float* __restrict__ out,
                            double* __restrict__ ws_acc) {
  int gid = blockIdx.x * blockDim.x + threadIdx.x;
  if (gid < Ln * Ln) out[OFF_GRAPH + gid] = 0.0f;
  if (gid < 17) ws_acc[gid] = 0.0;

  int r0 = blockIdx.x * 4;     // 512 blocks x 4 rows = 2048 rows
  int d = threadIdx.x;         // 0..255
  __shared__ float encS[4][Hn];
  ((float4*)encS)[d] = ((const float4*)(enc + (size_t)r0 * Hn))[d];
  __syncthreads();

  float al[4] = {0.f, 0.f, 0.f, 0.f};
  float ar[4] = {0.f, 0.f, 0.f, 0.f};
  for (int h4 = 0; h4 < Hn / 4; ++h4) {
    float4 e[4];
#pragma unroll
    for (int r = 0; r < 4; ++r) e[r] = ((const float4*)encS[r])[h4];
#pragma unroll
    for (int q = 0; q < 4; ++q) {
      int h = h4 * 4 + q;
      float wl = Wl[h * Dn + d];
      float wr = Wr[h * Dn + d];
#pragma unroll
      for (int r = 0; r < 4; ++r) {
        float ev = (q == 0) ? e[r].x : (q == 1) ? e[r].y : (q == 2) ? e[r].z : e[r].w;
        al[r] = fmaf(ev, wl, al[r]);
        ar[r] = fmaf(ev, wr, ar[r]);
      }
    }
  }
#pragma unroll
  for (int r = 0; r < 4; ++r) {
    dl[(size_t)(r0 + r) * Dn + d] = al[r];
    dr[(size_t)(r0 + r) * Dn + d] = ar[r];
  }
}

// Grid 1024 = (b:16, iq:32, jseg:2); block = 4 i-rows x 64 j x 256 d.
// 4 blocks/CU -> 16 waves/CU, ILP-4 accumulator chains per dr load,
// dl staged via ONE coalesced float4/thread into LDS then reg-cached.
// EXACT R9 form (best measured). Chunk-sum dp-ascending -> outputs
// bit-identical to R5/R8/R9.
__global__ void pair_kernel(const float* __restrict__ dl,
                            const float* __restrict__ dr,
                            const float* __restrict__ U,
                            const float* __restrict__ bias,
                            float* __restrict__ out,
                            double* __restrict__ ws_acc) {
  int blk = blockIdx.x;          // b*64 + iq*2 + jseg
  int b = blk >> 6;              // 0..15
  int i0 = ((blk >> 1) & 31) * 4;
  int j0 = (blk & 1) * 64;
  int t = threadIdx.x;
  int dp = t & 15;
  int jj = t >> 4;

  __shared__ float dlS[4][Dn];       // 4 KB, cooperative coalesced stage
  __shared__ float pS[4][4 * 256];   // [row][tl*256 + jj*16 + dp], 16 KB
  __shared__ float redS[8];

  // stage dl rows i0..i0+3 with one coalesced float4 load per thread
  ((float4*)dlS)[t] = ((const float4*)(dl + (size_t)(b * Ln + i0) * Dn))[t];

  float Ur[16];
  {
    const float4* U4 = (const float4*)(U + dp * 16);
#pragma unroll
    for (int q = 0; q < 4; ++q) {
      float4 u = U4[q];
      Ur[4*q+0] = u.x; Ur[4*q+1] = u.y; Ur[4*q+2] = u.z; Ur[4*q+3] = u.w;
    }
  }
  __syncthreads();

  float dlr[4][16];
#pragma unroll
  for (int r = 0; r < 4; ++r) {
#pragma unroll
    for (int q = 0; q < 4; ++q) {
      float4 a = *(const float4*)&dlS[r][dp * 16 + q * 4];
      dlr[r][4*q+0] = a.x; dlr[r][4*q+1] = a.y; dlr[r][4*q+2] = a.z; dlr[r][4*q+3] = a.w;
    }
  }

  const float* drt = dr + (size_t)b * Ln * Dn + (size_t)(j0 + jj) * Dn + dp * 16;
#pragma unroll
  for (int tl = 0; tl < 4; ++tl) {
    const float4* drp = (const float4*)(drt + (size_t)tl * 16 * Dn);
    float a0 = 0.f, a1 = 0.f, a2 = 0.f, a3 = 0.f;
#pragma unroll
    for (int q = 0; q < 4; ++q) {
      float4 v = drp[q];
#pragma unroll
      for (int c = 0; c < 4; ++c) {
        float dv = (c == 0) ? v.x : (c == 1) ? v.y : (c == 2) ? v.z : v.w;
        float uv = Ur[4*q+c];
        a0 = fmaf(fast_tanh(dlr[0][4*q+c] + dv), uv, a0);
        a1 = fmaf(fast_tanh(dlr[1][4*q+c] + dv), uv, a1);
        a2 = fmaf(fast_tanh(dlr[2][4*q+c] + dv), uv, a2);
        a3 = fmaf(fast_tanh(dlr[3][4*q+c] + dv), uv, a3);
      }
    }
    int sa = tl * 256 + jj * 16 + dp;    // == tl*256 + t : conflict-free
    pS[0][sa] = a0; pS[1][sa] = a1; pS[2][sa] = a2; pS[3][sa] = a3;
  }
  __syncthreads();

  // epilogue: 256 outputs (4 rows x 64 j); thread t -> row = t>>6, jl = t&63
  int row = t >> 6;
  int jl = t & 63;
  int j = j0 + jl;
  const float* ps = &pS[row][(jl >> 4) * 256 + (jl & 15) * 16];
  float tot = 0.0f;
#pragma unroll
  for (int k = 0; k < 16; ++k) tot += ps[k];   // dp-ascending, same as R9
  int i = i0 + row;
  float l = tot + bias[0] - ((j == i) ? 1.0e8f : 0.0f);
  float e = __expf(-l);                       // l=-1e8 -> inf
  float p = __builtin_amdgcn_rcpf(1.0f + e);  // -> 0 on diagonal
  unsigned n = ((unsigned)(b * Ln + i) << 7) | (unsigned)j;
  unsigned bits = threefry_bits(0u, n);
  float u = __uint_as_float((bits >> 9) | 0x3f800000u) - 1.0f;
  float smp = (u < p) ? 1.0f : 0.0f;
  float sp_pos = softplus_f(l);
  float sp_neg = softplus_f(-l);
  float ent = p * sp_neg + (1.0f - p) * sp_pos;
  size_t idx = (size_t)(b * Ln + i) * Ln + j;
  out[OFF_MASK + idx] = l;
  out[OFF_SMP + idx] = smp;
  out[OFF_ENT + idx] = ent;
  atomicAdd(&out[OFF_GRAPH + i * Ln + j], smp * 0.0625f);
  float ent_v = ent;
  float lse_v = sp_pos - l * smp;

  // reduce over the 4 waves (all lanes valid)
#pragma unroll
  for (int off = 32; off > 0; off >>= 1) {
    ent_v += __shfl_down(ent_v, off);
    lse_v += __shfl_down(lse_v, off);
  }
  if ((t & 63) == 0) {
    redS[(t >> 6) * 2 + 0] = ent_v;
    redS[(t >> 6) * 2 + 1] = lse_v;
  }
  __syncthreads();
  if (t == 0) {
    float es = redS[0] + redS[2] + redS[4] + redS[6];
    float ls = redS[1] + redS[3] + redS[5] + redS[7];
    atomicAdd(&ws_acc[b], (double)es);
    atomicAdd(&ws_acc[16], (double)ls);
  }
}

__global__ void finalize_kernel(const double* __restrict__ ws_acc, float* __restrict__ out) {
  int t = threadIdx.x;
  if (t == 0) out[OFF_LSE] = (float)(ws_acc[16] / (double)(Bn * Ln * Ln));
  if (t < Bn) out[OFF_EREG + t] = (float)(ws_acc[t] / (double)(Ln * Ln));
}

extern "C" void kernel_launch(void* const* d_in, const int* in_sizes, int n_in,
                              void* d_out, int out_size, void* d_ws, size_t ws_size,
                              hipStream_t stream) {
  const float* enc = (const float*)d_in[0];
  const float* Wl = (const float*)d_in[1];
  const float* Wr = (const float*)d_in[2];
  const float* U = (const float*)d_in[3];
  const float* bias = (const float*)d_in[4];
  float* out = (float*)d_out;

  // ws layout: dl (2048*256 f32), dr (2048*256 f32), accumulators (17 dbl)
  float* dl = (float*)d_ws;
  float* dr = dl + (size_t)Bn * Ln * Dn;
  double* ws_acc = (double*)(dr + (size_t)Bn * Ln * Dn);

  proj_kernel<<<Bn * Ln / 4, 256, 0, stream>>>(enc, Wl, Wr, dl, dr, out, ws_acc);
  pair_kernel<<<Bn * Ln / 2, 256, 0, stream>>>(dl, dr, U, bias, out, ws_acc);
  finalize_kernel<<<1, 64, 0, stream>>>(ws_acc, out);
}